// Round 17
// baseline (983.745 us; speedup 1.0000x reference)
//
#include <hip/hip_runtime.h>
#include <hip/hip_bf16.h>

// TensorizedRNN: m1/m2 = einsum('bj,bk,ljk->bl', h, x, W{1,2}) as bf16-MFMA GEMM
// with virtual A = h (outer) x, K = 1024*256 = 262144.
// B=1024, I2=256, H=512, N=1024 (W1||W2), J=1024.
//
// R17 = R13 retried with the RIGHT register attr. Unified-file model (from
// R16's flat result): waves/SIMD = 512 / (arch + AGPR). R15/16: 112+64=176
// -> 2 waves/SIMD (Occ 23%, no co-residency). R9: 64+32=96 -> 4-5 (Occ 47%).
// R13's shape was right (512thr, z-split, acc[4][2]) but (4,4) granted only
// 64 arch -> spill. Here:
//  - attr (2,4): grant ~112 arch (R15-proven), HW may pack 4 waves/SIMD.
//  - demand: xc packed 16 + hc 16 + bfr 16 + staging 16 + addr ~15 = ~80
//    arch + 32 AGPR = ~112/wave -> 4 waves/SIMD = 2 co-resident 512-thr
//    blocks with INDEPENDENT barriers (per-SIMD phase diversity).
//  - LDS 64 KB/block -> max 2 blocks/CU. grid (32,16,2): z-split batch;
//    W fetched 2x (~1.07 GB, fine at 8% HBM).
// Spill detector: WRITE_SIZE ~72 MB. Occ should read ~45%.

typedef __attribute__((ext_vector_type(8))) short short8;
typedef __attribute__((ext_vector_type(4))) float f32x4;
typedef __attribute__((ext_vector_type(2))) float f32x2;
typedef unsigned short ushort_t;

// f32 pair -> packed bf16 (low16 = a, high16 = b), single HW instr
__device__ __forceinline__ unsigned cvtpk(float a, float b) {
  unsigned r;
  asm("v_cvt_pk_bf16_f32 %0, %1, %2" : "=v"(r) : "v"(a), "v"(b));
  return r;
}

// packed f32 multiply, single HW instr
__device__ __forceinline__ f32x2 pkmul(f32x2 a, f32x2 b) {
  f32x2 r;
  asm("v_pk_mul_f32 %0, %1, %2" : "=v"(r) : "v"(a), "v"(b));
  return r;
}

__device__ __forceinline__ ushort_t f2bu(float f) {
  __hip_bfloat16 b = __float2bfloat16(f);
  union { __hip_bfloat16 b; ushort_t u; } cv;
  cv.b = b;
  return cv.u;
}

// ---------------- prep: hb16[b][j], xb16[b][kx], WmergeT[l][j] (all bf16) ---
__global__ void prep_k(const float* __restrict__ in0, const float* __restrict__ in1,
                       const float* __restrict__ s0, const float* __restrict__ s1,
                       const float* __restrict__ Wm,
                       ushort_t* __restrict__ hb, ushort_t* __restrict__ xb,
                       ushort_t* __restrict__ WmT) {
  __shared__ float tl[64][65];
  const int bid = blockIdx.x, t = threadIdx.x;
  if (bid < 256) {  // hb16: 1M elems, 4096/block
#pragma unroll
    for (int i = 0; i < 4; ++i) {
      int e = bid * 4096 + i * 1024 + t * 4;
      int b = e >> 10, j = e & 1023;
      const float* src = (j < 512) ? (s0 + (size_t)b * 512 + j)
                                   : (s1 + (size_t)b * 512 + j - 512);
      float4 v = *(const float4*)src;
      ushort4 o;
      o.x = f2bu(v.x); o.y = f2bu(v.y); o.z = f2bu(v.z); o.w = f2bu(v.w);
      *(ushort4*)(hb + e) = o;
    }
  } else if (bid < 272) {  // xb16: 256K elems, 16384/block
#pragma unroll
    for (int i = 0; i < 16; ++i) {
      int e = (bid - 256) * 16384 + i * 1024 + t * 4;
      int b = e >> 8, kx = e & 255;
      const float* src = (kx < 128) ? (in0 + (size_t)b * 128 + kx)
                                    : (in1 + (size_t)b * 128 + kx - 128);
      float4 v = *(const float4*)src;
      ushort4 o;
      o.x = f2bu(v.x); o.y = f2bu(v.y); o.z = f2bu(v.z); o.w = f2bu(v.w);
      *(ushort4*)(xb + e) = o;
    }
  } else {  // Wmerge [1024][512] -> WmT [512][1024], 64x64 tiles
    int q = bid - 272;           // 0..127
    int j0 = (q >> 3) * 64;
    int l0 = (q & 7) * 64;
#pragma unroll
    for (int i = 0; i < 16; ++i) {
      int idx = i * 256 + t; int r = idx >> 6, c = idx & 63;
      tl[r][c] = Wm[(size_t)(j0 + r) * 512 + l0 + c];
    }
    __syncthreads();
#pragma unroll
    for (int i = 0; i < 16; ++i) {
      int idx = i * 256 + t; int r = idx >> 6, c = idx & 63;
      WmT[(size_t)(l0 + r) * 1024 + j0 + c] = f2bu(tl[c][r]);
    }
  }
}

// ---------------- main bilinear GEMM --------------------------------------
// grid (32 ntiles, 16 kchunks, 2 mhalves) = 1024 blocks, 512 thr (8 waves),
// 2 blocks co-resident per CU. Block: 512 batch rows x 32 n-cols;
// K-chunk = 512 j's x 32 kx's, 64 stages of 8 j. Wave tile 64x32.
// Per stage: issue W(t+1) loads (16 f32/thread) -> compute 8 js
// (bfr reg-dbuf, 8 MFMA bursts) -> cvt+ds_write -> barrier.
__global__ __launch_bounds__(512)
__attribute__((amdgpu_waves_per_eu(2, 4))) void bilin_k(
    const float* __restrict__ W1, const float* __restrict__ W2,
    const ushort_t* __restrict__ hb, const ushort_t* __restrict__ xb,
    float* __restrict__ accg) {
  // 2 x 16 KB bf16 buffers + pad to 64 KB: at most 2 blocks/CU by LDS;
  // registers (112/wave x 4 waves/SIMD) make it exactly 2.
  __shared__ uint4 smemv[4096];  // 65536 B; buf i at byte i*16384

  const int ntile = blockIdx.x;         // 0..31 -> n cols ntile*32..+31
  const int chunk = blockIdx.y;         // 0..15
  const int mhalf = blockIdx.z;         // 0..1 -> batch rows mhalf*512..+511
  const int kxwin = (chunk & 7) * 32;   // kx window
  const int jbase0 = (chunk >> 3) * 512;
  const int tid = threadIdx.x;
  const int wave = tid >> 6;            // 0..7
  const int lane = tid & 63;
  const int l15 = lane & 15;
  const int lg = lane >> 4;
  const int wrow = mhalf * 512 + wave * 64;  // wave's 64 batch rows

  // W-staging role: col 0..31 (tid>>4), within-col c 0..15:
  //   j_sub = c>>1, half = c&1 -> 16 consecutive f32.
  const int scol = tid >> 4;
  const int cc = tid & 15;
  const int sjs = cc >> 1;
  const int shalf = cc & 1;
  const int swzw = (scol & 7) << 4;
  const int wb0 = scol * 512 + ((sjs * 64 + shalf * 32) ^ swzw);
  const int wb1 = scol * 512 + ((sjs * 64 + shalf * 32 + 16) ^ swzw);

  const float* Wsel = (ntile < 16) ? W1 : W2;
  const float* gW = Wsel + (size_t)((ntile & 15) * 32 + scol) * 262144 +
                    (size_t)(jbase0 + sjs) * 256 + kxwin + shalf * 16;
  // stage stride = 8 j * 256 = 2048 floats.

  // per-lane x cache, PACKED bf16 (t-invariant): 16 regs
  uint4 xc[4];
#pragma unroll
  for (int g = 0; g < 4; ++g)
    xc[g] = *(const uint4*)(xb + (size_t)(wrow + g * 16 + l15) * 256 + kxwin + lg * 8);

  f32x4 acc[4][2];
  const f32x4 z4 = {0.f, 0.f, 0.f, 0.f};
#pragma unroll
  for (int g = 0; g < 4; ++g)
#pragma unroll
    for (int nc = 0; nc < 2; ++nc) acc[g][nc] = z4;

  // prologue: stage t=0 into buf[0]
  {
    float4 v0 = *(const float4*)gW;
    float4 v1 = *(const float4*)(gW + 4);
    float4 v2 = *(const float4*)(gW + 8);
    float4 v3 = *(const float4*)(gW + 12);
    uint4 p0, p1;
    p0.x = cvtpk(v0.x, v0.y); p0.y = cvtpk(v0.z, v0.w);
    p0.z = cvtpk(v1.x, v1.y); p0.w = cvtpk(v1.z, v1.w);
    p1.x = cvtpk(v2.x, v2.y); p1.y = cvtpk(v2.z, v2.w);
    p1.z = cvtpk(v3.x, v3.y); p1.w = cvtpk(v3.z, v3.w);
    *(uint4*)((char*)smemv + wb0) = p0;
    *(uint4*)((char*)smemv + wb1) = p1;
  }
  __syncthreads();

  int cur = 0;
  for (int t = 0; t < 64; ++t) {
    const int nxt = cur ^ 1;
    // issue next-stage W loads early (drained after compute)
    float4 v0, v1, v2, v3;
    if (t < 63) {
      const float* gp = gW + (size_t)(t + 1) * 2048;
      v0 = *(const float4*)gp;
      v1 = *(const float4*)(gp + 4);
      v2 = *(const float4*)(gp + 8);
      v3 = *(const float4*)(gp + 12);
    }

    // h for this stage: 8 j's per row (16 B), 4 row-groups = 16 regs
    const int jw = jbase0 + t * 8;
    uint4 hc[4];
#pragma unroll
    for (int g = 0; g < 4; ++g)
      hc[g] = *(const uint4*)(hb + (size_t)(wrow + g * 16 + l15) * 1024 + jw);

    const char* rb = (const char*)smemv + cur * 16384;

    // register double-buffer for B fragments: preload js=0
    short8 bfr[2][2];
#pragma unroll
    for (int nc = 0; nc < 2; ++nc) {
      int col = nc * 16 + l15;
      int byte = col * 512 + ((lg * 16) ^ ((col & 7) << 4));
      bfr[0][nc] = *(const short8*)(rb + byte);
    }

#pragma unroll
    for (int js = 0; js < 8; ++js) {
      const int pb = js & 1, nb = pb ^ 1;
      if (js < 7) {
#pragma unroll
        for (int nc = 0; nc < 2; ++nc) {
          int col = nc * 16 + l15;
          int byte = col * 512 + (((js + 1) * 64 + lg * 16) ^ ((col & 7) << 4));
          bfr[nb][nc] = *(const short8*)(rb + byte);
        }
      }
      __builtin_amdgcn_s_setprio(1);
#pragma unroll
      for (int g = 0; g < 4; ++g) {
        unsigned hwrd = (js < 2) ? hc[g].x : (js < 4) ? hc[g].y
                       : (js < 6) ? hc[g].z : hc[g].w;
        float hf = __uint_as_float((js & 1) ? (hwrd & 0xFFFF0000u) : (hwrd << 16));
        f32x2 hf2; hf2[0] = hf; hf2[1] = hf;
        unsigned xw[4] = {xc[g].x, xc[g].y, xc[g].z, xc[g].w};
        union { unsigned u[4]; short8 s; } av;
#pragma unroll
        for (int p = 0; p < 4; ++p) {
          f32x2 xv;
          xv[0] = __uint_as_float(xw[p] << 16);
          xv[1] = __uint_as_float(xw[p] & 0xFFFF0000u);
          f32x2 m = pkmul(xv, hf2);
          av.u[p] = cvtpk(m[0], m[1]);
        }
        short8 afr = av.s;
#pragma unroll
        for (int nc = 0; nc < 2; ++nc)
          acc[g][nc] = __builtin_amdgcn_mfma_f32_16x16x32_bf16(
              afr, bfr[pb][nc], acc[g][nc], 0, 0, 0);
      }
      __builtin_amdgcn_s_setprio(0);
    }

    // write next stage (vmcnt wait lands here, after compute)
    if (t < 63) {
      uint4 p0, p1;
      p0.x = cvtpk(v0.x, v0.y); p0.y = cvtpk(v0.z, v0.w);
      p0.z = cvtpk(v1.x, v1.y); p0.w = cvtpk(v1.z, v1.w);
      p1.x = cvtpk(v2.x, v2.y); p1.y = cvtpk(v2.z, v2.w);
      p1.z = cvtpk(v3.x, v3.y); p1.w = cvtpk(v3.z, v3.w);
      *(uint4*)((char*)smemv + nxt * 16384 + wb0) = p0;
      *(uint4*)((char*)smemv + nxt * 16384 + wb1) = p1;
    }
    __syncthreads();
    cur = nxt;
  }

  // epilogue: split-K accumulate (16 adds per output elem over whole grid)
#pragma unroll
  for (int g = 0; g < 4; ++g)
#pragma unroll
    for (int nc = 0; nc < 2; ++nc)
#pragma unroll
      for (int r = 0; r < 4; ++r) {
        int b = wrow + g * 16 + lg * 4 + r;
        int n = ntile * 32 + nc * 16 + l15;
        unsafeAtomicAdd(&accg[(size_t)b * 1024 + n], acc[g][nc][r]);
      }
}

// ---------------- merge = h @ Wmerge (1024x512x1024 bf16 MFMA) -------------
__device__ __forceinline__ short8 ld8bf(const ushort_t* p) {
  union { uint4 v; short8 s; } cv;
  cv.v = *(const uint4*)p;
  return cv.s;
}

__global__ __launch_bounds__(256) void merge_k(const ushort_t* __restrict__ hb,
                                               const ushort_t* __restrict__ WmT,
                                               float* __restrict__ mout) {
  const int tid = threadIdx.x;
  const int wave = tid >> 6, lane = tid & 63;
  const int l15 = lane & 15, lg = lane >> 4;
  const int m0 = blockIdx.x * 64 + (wave >> 1) * 32;
  const int n0 = blockIdx.y * 64 + (wave & 1) * 32;
  const f32x4 z4 = {0.f, 0.f, 0.f, 0.f};
  f32x4 acc[2][2];
#pragma unroll
  for (int g = 0; g < 2; ++g)
#pragma unroll
    for (int nc = 0; nc < 2; ++nc) acc[g][nc] = z4;

  for (int k = 0; k < 1024; k += 32) {
    short8 af[2], bf[2];
#pragma unroll
    for (int g = 0; g < 2; ++g)
      af[g] = ld8bf(hb + (size_t)(m0 + g * 16 + l15) * 1024 + k + lg * 8);
#pragma unroll
    for (int nc = 0; nc < 2; ++nc)
      bf[nc] = ld8bf(WmT + (size_t)(n0 + nc * 16 + l15) * 1024 + k + lg * 8);
#pragma unroll
    for (int g = 0; g < 2; ++g)
#pragma unroll
      for (int nc = 0; nc < 2; ++nc)
        acc[g][nc] = __builtin_amdgcn_mfma_f32_16x16x32_bf16(
            af[g], bf[nc], acc[g][nc], 0, 0, 0);
  }
#pragma unroll
  for (int g = 0; g < 2; ++g)
#pragma unroll
    for (int nc = 0; nc < 2; ++nc)
#pragma unroll
      for (int r = 0; r < 4; ++r)
        mout[(size_t)(m0 + g * 16 + lg * 4 + r) * 512 + n0 + nc * 16 + l15] =
            acc[g][nc][r];
}

// ---------------- finalize -------------------------------------------------
__global__ void fin_k(const float* __restrict__ accg, const float* __restrict__ mout,
                      const float* __restrict__ b1, const float* __restrict__ b2,
                      float* __restrict__ out) {
  int idx = blockIdx.x * 256 + threadIdx.x;  // 524288 total
  int b = idx >> 9, l = idx & 511;
  float m1 = accg[(size_t)b * 1024 + l];
  float m2 = accg[(size_t)b * 1024 + 512 + l];
  float st = tanhf(m1 + b1[l]);
  float u = 1.f / (1.f + expf(-(m2 + b2[l])));
  out[idx] = u * st + (1.f - u) * mout[idx];
}

extern "C" void kernel_launch(void* const* d_in, const int* in_sizes, int n_in,
                              void* d_out, int out_size, void* d_ws, size_t ws_size,
                              hipStream_t stream) {
  const float* in0 = (const float*)d_in[0];
  const float* in1 = (const float*)d_in[1];
  const float* s0  = (const float*)d_in[2];
  const float* s1  = (const float*)d_in[3];
  const float* W1  = (const float*)d_in[4];
  const float* b1  = (const float*)d_in[5];
  const float* W2  = (const float*)d_in[6];
  const float* b2  = (const float*)d_in[7];
  const float* Wm  = (const float*)d_in[8];
  float* out = (float*)d_out;

  char* ws = (char*)d_ws;
  float*    accg = (float*)(ws + 0);                          // 4 MB
  float*    mout = (float*)(ws + (4u << 20));                 // 2 MB
  ushort_t* hb   = (ushort_t*)(ws + (6u << 20));              // 2 MB
  ushort_t* xb   = (ushort_t*)(ws + (8u << 20));              // 512 KB
  ushort_t* WmT  = (ushort_t*)(ws + (8u << 20) + (512u << 10)); // 1 MB

  hipMemsetAsync(accg, 0, 4u << 20, stream);
  prep_k<<<400, 256, 0, stream>>>(in0, in1, s0, s1, Wm, hb, xb, WmT);
  bilin_k<<<dim3(32, 16, 2), 512, 0, stream>>>(W1, W2, hb, xb, accg);
  merge_k<<<dim3(16, 8), 256, 0, stream>>>(hb, WmT, mout);
  fin_k<<<2048, 256, 0, stream>>>(accg, mout, b1, b2, out);
}